// Round 2
// baseline (526.585 us; speedup 1.0000x reference)
//
#include <hip/hip_runtime.h>
#include <math.h>

// Shapes fixed by reference setup_inputs()
constexpr int B  = 8;
constexpr int H  = 16;
constexpr int NT = 512;
constexpr int NV = 576;
constexpr int TILE = 64;
constexpr float INV_H2 = 1.0f / (float)(H * H);

constexpr int MN  = NT * NV;        // 294912 elements per (b,h) plane
constexpr int MN4 = MN / 4;         // 73728 float4 per plane
constexpr int W4  = B * MN4;        // 589824 float4 per tensor head-sum
constexpr int TOTAL4 = 4 * W4;      // 2359296 float4 outputs (t0,v0,t1,v1)

// Phase-1 blocking: each thread produces OUT4 float4 outputs; a block owns a
// contiguous 32 KB segment of every head plane -> sequential DRAM bursts.
constexpr int OUT4 = 8;
constexpr int SEG4 = 256 * OUT4;    // 2048 float4 = 32 KB per block per h
constexpr int SEGS = MN4 / SEG4;    // 36 segments per (tensor, b) plane

// accumulator layout: text_acc[2][B][NT] then vis_acc[2][B][NV]
constexpr int TEXT_N = 2 * B * NT;  // 8192
constexpr int VIS_N  = 2 * B * NV;  // 9216

// ---------------- Phase 1: head-sum reduction --------------------------
// Loop nest: h OUTER, segment INNER. Per h-step the block reads 32 KB of
// CONTIGUOUS memory (8 coalesced 4 KB rounds), then jumps to the next head
// plane. DRAM sees long sequential bursts instead of scattered 1 KB reads.
__global__ __launch_bounds__(256) void headsum_kernel(
    const float* __restrict__ t0, const float* __restrict__ v0,
    const float* __restrict__ t1, const float* __restrict__ v1,
    float4* __restrict__ S4)   // [4][B][MN4], order t0,v0,t1,v1
{
    const int bid  = blockIdx.x;           // 0 .. 4*B*SEGS-1
    const int seg  = bid % SEGS;
    const int rem  = bid / SEGS;
    const int b    = rem & (B - 1);
    const int tsel = rem >> 3;             // 0..3
    const float* __restrict__ src = (tsel == 0) ? t0 : (tsel == 1) ? v0
                                  : (tsel == 2) ? t1 : v1;

    const int p4 = seg * SEG4 + threadIdx.x;   // base float4 index in plane
    const float4* __restrict__ p =
        (const float4*)src + (size_t)b * (H * MN4) + p4;

    float4 acc[OUT4];
#pragma unroll
    for (int j = 0; j < OUT4; ++j) acc[j] = make_float4(0.f, 0.f, 0.f, 0.f);

    for (int h = 0; h < H; ++h) {
        const float4* __restrict__ q = p + (size_t)h * MN4;
        float4 x[OUT4];
#pragma unroll
        for (int j = 0; j < OUT4; ++j) x[j] = q[j * 256];
#pragma unroll
        for (int j = 0; j < OUT4; ++j) {
            acc[j].x += x[j].x; acc[j].y += x[j].y;
            acc[j].z += x[j].z; acc[j].w += x[j].w;
        }
    }

    float4* __restrict__ o = S4 + ((size_t)tsel * B + b) * MN4 + p4;
#pragma unroll
    for (int j = 0; j < OUT4; ++j) o[j * 256] = acc[j];
}

// ---------------- Phase 2: diagonal products ---------------------------
// One block per (k-tile, i-tile, b+B*layer). Reads the (small, L3-resident)
// head-sum planes, transposes the v tile through LDS, forms
// Q[ii][kk] = St[ii][kk] * Sv[kk][ii], reduces rows (-> text_diag) and
// cols (-> vision_diag), atomically accumulates to global ws.
__global__ __launch_bounds__(256) void diag_kernel(
    const float* __restrict__ S,   // [4][B][MN]
    float* __restrict__ text_acc,  // [2][B][NT]
    float* __restrict__ vis_acc)   // [2][B][NV]
{
    const int ktile = blockIdx.x;   // 0..NV/TILE-1
    const int itile = blockIdx.y;   // 0..NT/TILE-1
    const int bz    = blockIdx.z;   // 0..2*B-1
    const int b     = bz & (B - 1);
    const int layer = bz >> 3;

    const float* __restrict__ St = S + ((size_t)(2 * layer)     * B + b) * MN; // [NT][NV]
    const float* __restrict__ Sv = S + ((size_t)(2 * layer + 1) * B + b) * MN; // [NV][NT]

    const int tid = threadIdx.x;
    const int c = tid & 15;   // column group: floats 4c..4c+3
    const int g = tid >> 4;   // row group: rows g, g+16, g+32, g+48

    const int i0 = itile * TILE;
    const int k0 = ktile * TILE;

    float4 tacc[4];
    float4 vacc[4];
#pragma unroll
    for (int r = 0; r < 4; ++r) {
        const int row = g + 16 * r;
        tacc[r] = *(const float4*)(St + (size_t)(i0 + row) * NV + k0 + 4 * c);
        vacc[r] = *(const float4*)(Sv + (size_t)(k0 + row) * NT + i0 + 4 * c);
    }

    // LDS: v tile transposed access. Row stride 65 -> 2-way bank alias (free).
    __shared__ float vlds[TILE * 65];
    __shared__ float rowsum[TILE];
    __shared__ float colsum[TILE];

    if (tid < TILE) {
        rowsum[tid] = 0.0f;
        colsum[tid] = 0.0f;
    }

#pragma unroll
    for (int r = 0; r < 4; ++r) {
        const int kk = g + 16 * r;          // v row index (NV dim within tile)
        float* p = &vlds[kk * 65 + 4 * c];  // cols ii = 4c..4c+3 (NT dim)
        p[0] = vacc[r].x; p[1] = vacc[r].y; p[2] = vacc[r].z; p[3] = vacc[r].w;
    }
    __syncthreads();

    // Q[ii][kk] = St[ii][kk] * Sv[kk][ii]; thread's t element:
    // ii = g+16r, kk = 4c+j.
    float colpart[4] = {0.f, 0.f, 0.f, 0.f};
#pragma unroll
    for (int r = 0; r < 4; ++r) {
        const int ii = g + 16 * r;
        const float tq[4] = {tacc[r].x, tacc[r].y, tacc[r].z, tacc[r].w};
        float rp = 0.f;
#pragma unroll
        for (int j = 0; j < 4; ++j) {
            const int kk = 4 * c + j;
            const float q = tq[j] * vlds[kk * 65 + ii];
            rp += q;
            colpart[j] += q;
        }
        atomicAdd(&rowsum[ii], rp);
    }
#pragma unroll
    for (int j = 0; j < 4; ++j) {
        atomicAdd(&colsum[4 * c + j], colpart[j]);
    }
    __syncthreads();

    const int lb = layer * B + b;
    if (tid < TILE) {
        atomicAdd(&text_acc[(size_t)lb * NT + i0 + tid], rowsum[tid] * INV_H2);
    } else if (tid < 2 * TILE) {
        const int kk = tid - TILE;
        atomicAdd(&vis_acc[(size_t)lb * NV + k0 + kk], colsum[kk] * INV_H2);
    }
}

// ---------------- Fallback: original fused kernel ----------------------
// Used only if ws_size cannot hold the 37.7 MB head-sum intermediate.
__global__ __launch_bounds__(256) void fused_diag_kernel(
    const float* __restrict__ t0, const float* __restrict__ v0,
    const float* __restrict__ t1, const float* __restrict__ v1,
    float* __restrict__ text_acc,   // [2][B][NT]
    float* __restrict__ vis_acc)    // [2][B][NV]
{
    const int ktile = blockIdx.x;
    const int itile = blockIdx.y;
    const int bz    = blockIdx.z;
    const int b     = bz & (B - 1);
    const int layer = bz >> 3;

    const float* __restrict__ T = layer ? t1 : t0;
    const float* __restrict__ V = layer ? v1 : v0;

    const int tid = threadIdx.x;
    const int c = tid & 15;
    const int g = tid >> 4;

    const int i0 = itile * TILE;
    const int k0 = ktile * TILE;

    const size_t tbase = (size_t)b * H * NT * NV + (size_t)i0 * NV + k0;
    const size_t vbase = (size_t)b * H * NV * NT + (size_t)k0 * NT + i0;

    float4 tacc[4];
    float4 vacc[4];
#pragma unroll
    for (int r = 0; r < 4; ++r) {
        tacc[r] = make_float4(0.f, 0.f, 0.f, 0.f);
        vacc[r] = make_float4(0.f, 0.f, 0.f, 0.f);
    }

    for (int h = 0; h < H; ++h) {
        const float* tp = T + tbase + (size_t)h * NT * NV;
        const float* vp = V + vbase + (size_t)h * NV * NT;
#pragma unroll
        for (int r = 0; r < 4; ++r) {
            const int row = g + 16 * r;
            const float4 tv = *(const float4*)(tp + (size_t)row * NV + 4 * c);
            const float4 vv = *(const float4*)(vp + (size_t)row * NT + 4 * c);
            tacc[r].x += tv.x; tacc[r].y += tv.y; tacc[r].z += tv.z; tacc[r].w += tv.w;
            vacc[r].x += vv.x; vacc[r].y += vv.y; vacc[r].z += vv.z; vacc[r].w += vv.w;
        }
    }

    __shared__ float vlds[TILE * 65];
    __shared__ float rowsum[TILE];
    __shared__ float colsum[TILE];

    if (tid < TILE) {
        rowsum[tid] = 0.0f;
        colsum[tid] = 0.0f;
    }

#pragma unroll
    for (int r = 0; r < 4; ++r) {
        const int kk = g + 16 * r;
        float* p = &vlds[kk * 65 + 4 * c];
        p[0] = vacc[r].x; p[1] = vacc[r].y; p[2] = vacc[r].z; p[3] = vacc[r].w;
    }
    __syncthreads();

    float colpart[4] = {0.f, 0.f, 0.f, 0.f};
#pragma unroll
    for (int r = 0; r < 4; ++r) {
        const int ii = g + 16 * r;
        const float tq[4] = {tacc[r].x, tacc[r].y, tacc[r].z, tacc[r].w};
        float rp = 0.f;
#pragma unroll
        for (int j = 0; j < 4; ++j) {
            const int kk = 4 * c + j;
            const float q = tq[j] * vlds[kk * 65 + ii];
            rp += q;
            colpart[j] += q;
        }
        atomicAdd(&rowsum[ii], rp);
    }
#pragma unroll
    for (int j = 0; j < 4; ++j) {
        atomicAdd(&colsum[4 * c + j], colpart[j]);
    }
    __syncthreads();

    const int lb = layer * B + b;
    if (tid < TILE) {
        atomicAdd(&text_acc[(size_t)lb * NT + i0 + tid], rowsum[tid] * INV_H2);
    } else if (tid < 2 * TILE) {
        const int kk = tid - TILE;
        atomicAdd(&vis_acc[(size_t)lb * NV + k0 + kk], colsum[kk] * INV_H2);
    }
}

// Single block: weighted sum of -log(clip(x)) over all diag entries.
__global__ __launch_bounds__(256) void finalize_kernel(
    const float* __restrict__ text_acc,
    const float* __restrict__ vis_acc,
    float* __restrict__ out)
{
    const int tid = threadIdx.x;
    const float wt = 0.25f / (float)(B * NT);
    const float wv = 0.25f / (float)(B * NV);

    float s = 0.f;
    for (int i = tid; i < TEXT_N; i += 256) {
        float x = text_acc[i];
        x = fminf(fmaxf(x, 1e-8f), 1.0f);
        s += -logf(x) * wt;
    }
    for (int i = tid; i < VIS_N; i += 256) {
        float x = vis_acc[i];
        x = fminf(fmaxf(x, 1e-8f), 1.0f);
        s += -logf(x) * wv;
    }

#pragma unroll
    for (int off = 32; off > 0; off >>= 1) s += __shfl_down(s, off, 64);

    __shared__ float wsum[4];
    if ((tid & 63) == 0) wsum[tid >> 6] = s;
    __syncthreads();
    if (tid == 0) out[0] = wsum[0] + wsum[1] + wsum[2] + wsum[3];
}

extern "C" void kernel_launch(void* const* d_in, const int* in_sizes, int n_in,
                              void* d_out, int out_size, void* d_ws, size_t ws_size,
                              hipStream_t stream) {
    const float* t0 = (const float*)d_in[0];
    const float* v0 = (const float*)d_in[1];
    const float* t1 = (const float*)d_in[2];
    const float* v1 = (const float*)d_in[3];
    float* out = (float*)d_out;

    constexpr size_t S_FLOATS = (size_t)4 * B * MN;                 // 9,437,184
    constexpr size_t NEED = (S_FLOATS + TEXT_N + VIS_N) * sizeof(float);

    if (ws_size >= NEED) {
        // -------- phase-split path --------
        float* S        = (float*)d_ws;
        float* text_acc = S + S_FLOATS;
        float* vis_acc  = text_acc + TEXT_N;

        hipMemsetAsync(text_acc, 0, (TEXT_N + VIS_N) * sizeof(float), stream);

        headsum_kernel<<<4 * B * SEGS, 256, 0, stream>>>(t0, v0, t1, v1, (float4*)S);
        {
            dim3 grid(NV / TILE, NT / TILE, 2 * B);  // (9, 8, 16)
            diag_kernel<<<grid, 256, 0, stream>>>(S, text_acc, vis_acc);
        }
        finalize_kernel<<<1, 256, 0, stream>>>(text_acc, vis_acc, out);
    } else {
        // -------- fallback: original fused path --------
        float* text_acc = (float*)d_ws;
        float* vis_acc  = text_acc + TEXT_N;

        hipMemsetAsync(text_acc, 0, (TEXT_N + VIS_N) * sizeof(float), stream);
        {
            dim3 grid(NV / TILE, NT / TILE, 2 * B);
            fused_diag_kernel<<<grid, 256, 0, stream>>>(t0, v0, t1, v1, text_acc, vis_acc);
        }
        finalize_kernel<<<1, 256, 0, stream>>>(text_acc, vis_acc, out);
    }
}

// Round 4
// 499.625 us; speedup vs baseline: 1.0540x; 1.0540x over previous
//
#include <hip/hip_runtime.h>
#include <math.h>

// Shapes fixed by reference setup_inputs()
constexpr int B  = 8;
constexpr int H  = 16;
constexpr int NT = 512;
constexpr int NV = 576;
constexpr int TILE = 64;
constexpr float INV_H2 = 1.0f / (float)(H * H);

constexpr int MN  = NT * NV;        // 294912 elements per (b,h) plane
constexpr int MN4 = MN / 4;         // 73728 float4 per plane
constexpr int W4  = B * MN4;        // 589824 float4 per tensor head-sum
constexpr int TOTAL4 = 4 * W4;      // 2359296 float4 outputs (t0,v0,t1,v1)

// Phase-1 blocking: OUT4 float4 per thread; 2304 blocks = 9 blocks/CU exactly.
// Balances wave-level MLP / work-per-wave (round-2 lesson) against grid size
// (round-1 lesson: 1152 blocks grid-capped occupancy at 39%).
constexpr int OUT4 = 4;
constexpr int SEG4 = 256 * OUT4;    // 1024 float4 = 16 KB of outputs per block
constexpr int SEGS = MN4 / SEG4;    // 72 segments per (tensor, b) plane
constexpr int NBLK = TOTAL4 / SEG4; // 2304 blocks

// Native vector type: __builtin_nontemporal_load requires a native vector,
// not HIP's HIP_vector_type<float,4> class.
typedef float f32x4 __attribute__((ext_vector_type(4)));

// accumulator layout: text_acc[2][B][NT] then vis_acc[2][B][NV]
constexpr int TEXT_N = 2 * B * NT;  // 8192
constexpr int VIS_N  = 2 * B * NV;  // 9216

// ---------------- Phase 1: head-sum reduction --------------------------
// Each thread: 4 float4 outputs, 64 nontemporal loads (h-loop unrolled x2 ->
// up to 8 dwordx4 in flight). Inputs are read-once: nontemporal avoids
// polluting L2/L3; the S output stays cached for the diag phase.
__global__ __launch_bounds__(256) void headsum_kernel(
    const float* __restrict__ t0, const float* __restrict__ v0,
    const float* __restrict__ t1, const float* __restrict__ v1,
    float* __restrict__ S)   // [4][B][MN], order t0,v0,t1,v1
{
    const int bid  = blockIdx.x;           // 0 .. NBLK-1
    const int seg  = bid % SEGS;
    const int rem  = bid / SEGS;
    const int b    = rem & (B - 1);
    const int tsel = rem >> 3;             // 0..3
    const float* __restrict__ src = (tsel == 0) ? t0 : (tsel == 1) ? v0
                                  : (tsel == 2) ? t1 : v1;

    const int p4 = seg * SEG4 + threadIdx.x;   // base float4 index in plane
    const f32x4* __restrict__ p =
        (const f32x4*)src + (size_t)b * (H * MN4) + p4;

    f32x4 acc[OUT4];
#pragma unroll
    for (int j = 0; j < OUT4; ++j) acc[j] = (f32x4)(0.f);

#pragma unroll 2
    for (int h = 0; h < H; ++h) {
        const f32x4* __restrict__ q = p + (size_t)h * MN4;
        f32x4 x[OUT4];
#pragma unroll
        for (int j = 0; j < OUT4; ++j)
            x[j] = __builtin_nontemporal_load(&q[j * 256]);
#pragma unroll
        for (int j = 0; j < OUT4; ++j)
            acc[j] += x[j];
    }

    f32x4* __restrict__ o = (f32x4*)S + ((size_t)tsel * B + b) * MN4 + p4;
#pragma unroll
    for (int j = 0; j < OUT4; ++j) o[j * 256] = acc[j];
}

// ---------------- Phase 2: diagonal products ---------------------------
// One block per (k-tile, i-tile, b+B*layer). Reads the (small, mostly
// L2/L3-resident) head-sum planes, transposes the v tile through LDS, forms
// Q[ii][kk] = St[ii][kk] * Sv[kk][ii], reduces rows (-> text_diag) and
// cols (-> vision_diag), atomically accumulates to global ws.
__global__ __launch_bounds__(256) void diag_kernel(
    const float* __restrict__ S,   // [4][B][MN]
    float* __restrict__ text_acc,  // [2][B][NT]
    float* __restrict__ vis_acc)   // [2][B][NV]
{
    const int ktile = blockIdx.x;   // 0..NV/TILE-1
    const int itile = blockIdx.y;   // 0..NT/TILE-1
    const int bz    = blockIdx.z;   // 0..2*B-1
    const int b     = bz & (B - 1);
    const int layer = bz >> 3;

    const float* __restrict__ St = S + ((size_t)(2 * layer)     * B + b) * MN; // [NT][NV]
    const float* __restrict__ Sv = S + ((size_t)(2 * layer + 1) * B + b) * MN; // [NV][NT]

    const int tid = threadIdx.x;
    const int c = tid & 15;   // column group: floats 4c..4c+3
    const int g = tid >> 4;   // row group: rows g, g+16, g+32, g+48

    const int i0 = itile * TILE;
    const int k0 = ktile * TILE;

    float4 tacc[4];
    float4 vacc[4];
#pragma unroll
    for (int r = 0; r < 4; ++r) {
        const int row = g + 16 * r;
        tacc[r] = *(const float4*)(St + (size_t)(i0 + row) * NV + k0 + 4 * c);
        vacc[r] = *(const float4*)(Sv + (size_t)(k0 + row) * NT + i0 + 4 * c);
    }

    // LDS: v tile transposed access. Row stride 65 -> 2-way bank alias (free).
    __shared__ float vlds[TILE * 65];
    __shared__ float rowsum[TILE];
    __shared__ float colsum[TILE];

    if (tid < TILE) {
        rowsum[tid] = 0.0f;
        colsum[tid] = 0.0f;
    }

#pragma unroll
    for (int r = 0; r < 4; ++r) {
        const int kk = g + 16 * r;          // v row index (NV dim within tile)
        float* p = &vlds[kk * 65 + 4 * c];  // cols ii = 4c..4c+3 (NT dim)
        p[0] = vacc[r].x; p[1] = vacc[r].y; p[2] = vacc[r].z; p[3] = vacc[r].w;
    }
    __syncthreads();

    // Q[ii][kk] = St[ii][kk] * Sv[kk][ii]; thread's t element:
    // ii = g+16r, kk = 4c+j.
    float colpart[4] = {0.f, 0.f, 0.f, 0.f};
#pragma unroll
    for (int r = 0; r < 4; ++r) {
        const int ii = g + 16 * r;
        const float tq[4] = {tacc[r].x, tacc[r].y, tacc[r].z, tacc[r].w};
        float rp = 0.f;
#pragma unroll
        for (int j = 0; j < 4; ++j) {
            const int kk = 4 * c + j;
            const float q = tq[j] * vlds[kk * 65 + ii];
            rp += q;
            colpart[j] += q;
        }
        atomicAdd(&rowsum[ii], rp);
    }
#pragma unroll
    for (int j = 0; j < 4; ++j) {
        atomicAdd(&colsum[4 * c + j], colpart[j]);
    }
    __syncthreads();

    const int lb = layer * B + b;
    if (tid < TILE) {
        atomicAdd(&text_acc[(size_t)lb * NT + i0 + tid], rowsum[tid] * INV_H2);
    } else if (tid < 2 * TILE) {
        const int kk = tid - TILE;
        atomicAdd(&vis_acc[(size_t)lb * NV + k0 + kk], colsum[kk] * INV_H2);
    }
}

// ---------------- Fallback: original fused kernel ----------------------
// Used only if ws_size cannot hold the 37.7 MB head-sum intermediate.
__global__ __launch_bounds__(256) void fused_diag_kernel(
    const float* __restrict__ t0, const float* __restrict__ v0,
    const float* __restrict__ t1, const float* __restrict__ v1,
    float* __restrict__ text_acc,   // [2][B][NT]
    float* __restrict__ vis_acc)    // [2][B][NV]
{
    const int ktile = blockIdx.x;
    const int itile = blockIdx.y;
    const int bz    = blockIdx.z;
    const int b     = bz & (B - 1);
    const int layer = bz >> 3;

    const float* __restrict__ T = layer ? t1 : t0;
    const float* __restrict__ V = layer ? v1 : v0;

    const int tid = threadIdx.x;
    const int c = tid & 15;
    const int g = tid >> 4;

    const int i0 = itile * TILE;
    const int k0 = ktile * TILE;

    const size_t tbase = (size_t)b * H * NT * NV + (size_t)i0 * NV + k0;
    const size_t vbase = (size_t)b * H * NV * NT + (size_t)k0 * NT + i0;

    float4 tacc[4];
    float4 vacc[4];
#pragma unroll
    for (int r = 0; r < 4; ++r) {
        tacc[r] = make_float4(0.f, 0.f, 0.f, 0.f);
        vacc[r] = make_float4(0.f, 0.f, 0.f, 0.f);
    }

    for (int h = 0; h < H; ++h) {
        const float* tp = T + tbase + (size_t)h * NT * NV;
        const float* vp = V + vbase + (size_t)h * NV * NT;
#pragma unroll
        for (int r = 0; r < 4; ++r) {
            const int row = g + 16 * r;
            const float4 tv = *(const float4*)(tp + (size_t)row * NV + 4 * c);
            const float4 vv = *(const float4*)(vp + (size_t)row * NT + 4 * c);
            tacc[r].x += tv.x; tacc[r].y += tv.y; tacc[r].z += tv.z; tacc[r].w += tv.w;
            vacc[r].x += vv.x; vacc[r].y += vv.y; vacc[r].z += vv.z; vacc[r].w += vv.w;
        }
    }

    __shared__ float vlds[TILE * 65];
    __shared__ float rowsum[TILE];
    __shared__ float colsum[TILE];

    if (tid < TILE) {
        rowsum[tid] = 0.0f;
        colsum[tid] = 0.0f;
    }

#pragma unroll
    for (int r = 0; r < 4; ++r) {
        const int kk = g + 16 * r;
        float* p = &vlds[kk * 65 + 4 * c];
        p[0] = vacc[r].x; p[1] = vacc[r].y; p[2] = vacc[r].z; p[3] = vacc[r].w;
    }
    __syncthreads();

    float colpart[4] = {0.f, 0.f, 0.f, 0.f};
#pragma unroll
    for (int r = 0; r < 4; ++r) {
        const int ii = g + 16 * r;
        const float tq[4] = {tacc[r].x, tacc[r].y, tacc[r].z, tacc[r].w};
        float rp = 0.f;
#pragma unroll
        for (int j = 0; j < 4; ++j) {
            const int kk = 4 * c + j;
            const float q = tq[j] * vlds[kk * 65 + ii];
            rp += q;
            colpart[j] += q;
        }
        atomicAdd(&rowsum[ii], rp);
    }
#pragma unroll
    for (int j = 0; j < 4; ++j) {
        atomicAdd(&colsum[4 * c + j], colpart[j]);
    }
    __syncthreads();

    const int lb = layer * B + b;
    if (tid < TILE) {
        atomicAdd(&text_acc[(size_t)lb * NT + i0 + tid], rowsum[tid] * INV_H2);
    } else if (tid < 2 * TILE) {
        const int kk = tid - TILE;
        atomicAdd(&vis_acc[(size_t)lb * NV + k0 + kk], colsum[kk] * INV_H2);
    }
}

// Single block: weighted sum of -log(clip(x)) over all diag entries.
__global__ __launch_bounds__(256) void finalize_kernel(
    const float* __restrict__ text_acc,
    const float* __restrict__ vis_acc,
    float* __restrict__ out)
{
    const int tid = threadIdx.x;
    const float wt = 0.25f / (float)(B * NT);
    const float wv = 0.25f / (float)(B * NV);

    float s = 0.f;
    for (int i = tid; i < TEXT_N; i += 256) {
        float x = text_acc[i];
        x = fminf(fmaxf(x, 1e-8f), 1.0f);
        s += -logf(x) * wt;
    }
    for (int i = tid; i < VIS_N; i += 256) {
        float x = vis_acc[i];
        x = fminf(fmaxf(x, 1e-8f), 1.0f);
        s += -logf(x) * wv;
    }

#pragma unroll
    for (int off = 32; off > 0; off >>= 1) s += __shfl_down(s, off, 64);

    __shared__ float wsum[4];
    if ((tid & 63) == 0) wsum[tid >> 6] = s;
    __syncthreads();
    if (tid == 0) out[0] = wsum[0] + wsum[1] + wsum[2] + wsum[3];
}

extern "C" void kernel_launch(void* const* d_in, const int* in_sizes, int n_in,
                              void* d_out, int out_size, void* d_ws, size_t ws_size,
                              hipStream_t stream) {
    const float* t0 = (const float*)d_in[0];
    const float* v0 = (const float*)d_in[1];
    const float* t1 = (const float*)d_in[2];
    const float* v1 = (const float*)d_in[3];
    float* out = (float*)d_out;

    constexpr size_t S_FLOATS = (size_t)4 * B * MN;                 // 9,437,184
    constexpr size_t NEED = (S_FLOATS + TEXT_N + VIS_N) * sizeof(float);

    if (ws_size >= NEED) {
        // -------- phase-split path --------
        float* S        = (float*)d_ws;
        float* text_acc = S + S_FLOATS;
        float* vis_acc  = text_acc + TEXT_N;

        (void)hipMemsetAsync(text_acc, 0, (TEXT_N + VIS_N) * sizeof(float), stream);

        headsum_kernel<<<NBLK, 256, 0, stream>>>(t0, v0, t1, v1, S);
        {
            dim3 grid(NV / TILE, NT / TILE, 2 * B);  // (9, 8, 16)
            diag_kernel<<<grid, 256, 0, stream>>>(S, text_acc, vis_acc);
        }
        finalize_kernel<<<1, 256, 0, stream>>>(text_acc, vis_acc, out);
    } else {
        // -------- fallback: original fused path --------
        float* text_acc = (float*)d_ws;
        float* vis_acc  = text_acc + TEXT_N;

        (void)hipMemsetAsync(text_acc, 0, (TEXT_N + VIS_N) * sizeof(float), stream);
        {
            dim3 grid(NV / TILE, NT / TILE, 2 * B);
            fused_diag_kernel<<<grid, 256, 0, stream>>>(t0, v0, t1, v1, text_acc, vis_acc);
        }
        finalize_kernel<<<1, 256, 0, stream>>>(text_acc, vis_acc, out);
    }
}

// Round 5
// 495.872 us; speedup vs baseline: 1.0619x; 1.0076x over previous
//
#include <hip/hip_runtime.h>
#include <math.h>

// Shapes fixed by reference setup_inputs()
constexpr int B  = 8;
constexpr int H  = 16;
constexpr int NT = 512;
constexpr int NV = 576;
constexpr int TILE = 64;
constexpr float INV_H2 = 1.0f / (float)(H * H);

constexpr int MN  = NT * NV;        // 294912 elements per (b,h) plane
constexpr int MN4 = MN / 4;         // 73728 float4 per plane
constexpr int W4  = B * MN4;        // 589824 float4 per tensor head-sum
constexpr int TOTAL4 = 4 * W4;      // 2359296 float4 outputs (t0,v0,t1,v1)

// Phase-1 blocking: OUT4 float4 per thread; 2304 blocks = 9 blocks/CU exactly.
constexpr int OUT4 = 4;
constexpr int SEG4 = 256 * OUT4;    // 1024 float4 = 16 KB of outputs per block
constexpr int SEGS = MN4 / SEG4;    // 72 segments per (tensor, b) plane
constexpr int NBLK = TOTAL4 / SEG4; // 2304 blocks

// Native vector type: __builtin_nontemporal_load requires a native vector,
// not HIP's HIP_vector_type<float,4> class.
typedef float f32x4 __attribute__((ext_vector_type(4)));

// accumulator layout: text_acc[2][B][NT] then vis_acc[2][B][NV]
constexpr int TEXT_N = 2 * B * NT;  // 8192
constexpr int VIS_N  = 2 * B * NV;  // 9216
constexpr int ACC_N  = TEXT_N + VIS_N;          // 17408 = 68 * 256
constexpr int ZERO_BLKS = ACC_N / 256;          // 68 blocks zero the accs

// ---------------- Phase 1: head-sum reduction --------------------------
// Each thread: 4 float4 outputs, 64 nontemporal loads (h-loop unrolled x4 ->
// up to 16 dwordx4 in flight). Inputs are read-once: nontemporal avoids
// polluting L2/L3; the S output stays cached (regular stores) for phase 2.
// Blocks 0..67 additionally zero the 17408-float accumulator region,
// replacing the separate memset dispatch (stream-ordered before diag).
__global__ __launch_bounds__(256) void headsum_kernel(
    const float* __restrict__ t0, const float* __restrict__ v0,
    const float* __restrict__ t1, const float* __restrict__ v1,
    float* __restrict__ S,       // [4][B][MN], order t0,v0,t1,v1
    float* __restrict__ acc_ws)  // [ACC_N] accumulators to zero
{
    const int bid  = blockIdx.x;           // 0 .. NBLK-1
    if (bid < ZERO_BLKS) {
        acc_ws[bid * 256 + threadIdx.x] = 0.0f;
    }

    const int seg  = bid % SEGS;
    const int rem  = bid / SEGS;
    const int b    = rem & (B - 1);
    const int tsel = rem >> 3;             // 0..3
    const float* __restrict__ src = (tsel == 0) ? t0 : (tsel == 1) ? v0
                                  : (tsel == 2) ? t1 : v1;

    const int p4 = seg * SEG4 + threadIdx.x;   // base float4 index in plane
    const f32x4* __restrict__ p =
        (const f32x4*)src + (size_t)b * (H * MN4) + p4;

    f32x4 acc[OUT4];
#pragma unroll
    for (int j = 0; j < OUT4; ++j) acc[j] = (f32x4)(0.f);

#pragma unroll 4
    for (int h = 0; h < H; ++h) {
        const f32x4* __restrict__ q = p + (size_t)h * MN4;
        f32x4 x[OUT4];
#pragma unroll
        for (int j = 0; j < OUT4; ++j)
            x[j] = __builtin_nontemporal_load(&q[j * 256]);
#pragma unroll
        for (int j = 0; j < OUT4; ++j)
            acc[j] += x[j];
    }

    f32x4* __restrict__ o = (f32x4*)S + ((size_t)tsel * B + b) * MN4 + p4;
#pragma unroll
    for (int j = 0; j < OUT4; ++j) o[j * 256] = acc[j];
}

// ---------------- Phase 2: diagonal products ---------------------------
// One block per (k-tile, i-tile, b+B*layer). Reads the (small, mostly
// L2/L3-resident) head-sum planes, transposes the v tile through LDS, forms
// Q[ii][kk] = St[ii][kk] * Sv[kk][ii], reduces rows (-> text_diag) and
// cols (-> vision_diag), atomically accumulates to global ws.
__global__ __launch_bounds__(256) void diag_kernel(
    const float* __restrict__ S,   // [4][B][MN]
    float* __restrict__ text_acc,  // [2][B][NT]
    float* __restrict__ vis_acc)   // [2][B][NV]
{
    const int ktile = blockIdx.x;   // 0..NV/TILE-1
    const int itile = blockIdx.y;   // 0..NT/TILE-1
    const int bz    = blockIdx.z;   // 0..2*B-1
    const int b     = bz & (B - 1);
    const int layer = bz >> 3;

    const float* __restrict__ St = S + ((size_t)(2 * layer)     * B + b) * MN; // [NT][NV]
    const float* __restrict__ Sv = S + ((size_t)(2 * layer + 1) * B + b) * MN; // [NV][NT]

    const int tid = threadIdx.x;
    const int c = tid & 15;   // column group: floats 4c..4c+3
    const int g = tid >> 4;   // row group: rows g, g+16, g+32, g+48

    const int i0 = itile * TILE;
    const int k0 = ktile * TILE;

    float4 tacc[4];
    float4 vacc[4];
#pragma unroll
    for (int r = 0; r < 4; ++r) {
        const int row = g + 16 * r;
        tacc[r] = *(const float4*)(St + (size_t)(i0 + row) * NV + k0 + 4 * c);
        vacc[r] = *(const float4*)(Sv + (size_t)(k0 + row) * NT + i0 + 4 * c);
    }

    // LDS: v tile transposed access. Row stride 65 -> 2-way bank alias (free).
    __shared__ float vlds[TILE * 65];
    __shared__ float rowsum[TILE];
    __shared__ float colsum[TILE];

    if (tid < TILE) {
        rowsum[tid] = 0.0f;
        colsum[tid] = 0.0f;
    }

#pragma unroll
    for (int r = 0; r < 4; ++r) {
        const int kk = g + 16 * r;          // v row index (NV dim within tile)
        float* p = &vlds[kk * 65 + 4 * c];  // cols ii = 4c..4c+3 (NT dim)
        p[0] = vacc[r].x; p[1] = vacc[r].y; p[2] = vacc[r].z; p[3] = vacc[r].w;
    }
    __syncthreads();

    // Q[ii][kk] = St[ii][kk] * Sv[kk][ii]; thread's t element:
    // ii = g+16r, kk = 4c+j.
    float colpart[4] = {0.f, 0.f, 0.f, 0.f};
#pragma unroll
    for (int r = 0; r < 4; ++r) {
        const int ii = g + 16 * r;
        const float tq[4] = {tacc[r].x, tacc[r].y, tacc[r].z, tacc[r].w};
        float rp = 0.f;
#pragma unroll
        for (int j = 0; j < 4; ++j) {
            const int kk = 4 * c + j;
            const float q = tq[j] * vlds[kk * 65 + ii];
            rp += q;
            colpart[j] += q;
        }
        atomicAdd(&rowsum[ii], rp);
    }
#pragma unroll
    for (int j = 0; j < 4; ++j) {
        atomicAdd(&colsum[4 * c + j], colpart[j]);
    }
    __syncthreads();

    const int lb = layer * B + b;
    if (tid < TILE) {
        atomicAdd(&text_acc[(size_t)lb * NT + i0 + tid], rowsum[tid] * INV_H2);
    } else if (tid < 2 * TILE) {
        const int kk = tid - TILE;
        atomicAdd(&vis_acc[(size_t)lb * NV + k0 + kk], colsum[kk] * INV_H2);
    }
}

// ---------------- Fallback: original fused kernel ----------------------
// Used only if ws_size cannot hold the 37.7 MB head-sum intermediate.
__global__ __launch_bounds__(256) void fused_diag_kernel(
    const float* __restrict__ t0, const float* __restrict__ v0,
    const float* __restrict__ t1, const float* __restrict__ v1,
    float* __restrict__ text_acc,   // [2][B][NT]
    float* __restrict__ vis_acc)    // [2][B][NV]
{
    const int ktile = blockIdx.x;
    const int itile = blockIdx.y;
    const int bz    = blockIdx.z;
    const int b     = bz & (B - 1);
    const int layer = bz >> 3;

    const float* __restrict__ T = layer ? t1 : t0;
    const float* __restrict__ V = layer ? v1 : v0;

    const int tid = threadIdx.x;
    const int c = tid & 15;
    const int g = tid >> 4;

    const int i0 = itile * TILE;
    const int k0 = ktile * TILE;

    const size_t tbase = (size_t)b * H * NT * NV + (size_t)i0 * NV + k0;
    const size_t vbase = (size_t)b * H * NV * NT + (size_t)k0 * NT + i0;

    float4 tacc[4];
    float4 vacc[4];
#pragma unroll
    for (int r = 0; r < 4; ++r) {
        tacc[r] = make_float4(0.f, 0.f, 0.f, 0.f);
        vacc[r] = make_float4(0.f, 0.f, 0.f, 0.f);
    }

    for (int h = 0; h < H; ++h) {
        const float* tp = T + tbase + (size_t)h * NT * NV;
        const float* vp = V + vbase + (size_t)h * NV * NT;
#pragma unroll
        for (int r = 0; r < 4; ++r) {
            const int row = g + 16 * r;
            const float4 tv = *(const float4*)(tp + (size_t)row * NV + 4 * c);
            const float4 vv = *(const float4*)(vp + (size_t)row * NT + 4 * c);
            tacc[r].x += tv.x; tacc[r].y += tv.y; tacc[r].z += tv.z; tacc[r].w += tv.w;
            vacc[r].x += vv.x; vacc[r].y += vv.y; vacc[r].z += vv.z; vacc[r].w += vv.w;
        }
    }

    __shared__ float vlds[TILE * 65];
    __shared__ float rowsum[TILE];
    __shared__ float colsum[TILE];

    if (tid < TILE) {
        rowsum[tid] = 0.0f;
        colsum[tid] = 0.0f;
    }

#pragma unroll
    for (int r = 0; r < 4; ++r) {
        const int kk = g + 16 * r;
        float* p = &vlds[kk * 65 + 4 * c];
        p[0] = vacc[r].x; p[1] = vacc[r].y; p[2] = vacc[r].z; p[3] = vacc[r].w;
    }
    __syncthreads();

    float colpart[4] = {0.f, 0.f, 0.f, 0.f};
#pragma unroll
    for (int r = 0; r < 4; ++r) {
        const int ii = g + 16 * r;
        const float tq[4] = {tacc[r].x, tacc[r].y, tacc[r].z, tacc[r].w};
        float rp = 0.f;
#pragma unroll
        for (int j = 0; j < 4; ++j) {
            const int kk = 4 * c + j;
            const float q = tq[j] * vlds[kk * 65 + ii];
            rp += q;
            colpart[j] += q;
        }
        atomicAdd(&rowsum[ii], rp);
    }
#pragma unroll
    for (int j = 0; j < 4; ++j) {
        atomicAdd(&colsum[4 * c + j], colpart[j]);
    }
    __syncthreads();

    const int lb = layer * B + b;
    if (tid < TILE) {
        atomicAdd(&text_acc[(size_t)lb * NT + i0 + tid], rowsum[tid] * INV_H2);
    } else if (tid < 2 * TILE) {
        const int kk = tid - TILE;
        atomicAdd(&vis_acc[(size_t)lb * NV + k0 + kk], colsum[kk] * INV_H2);
    }
}

// Single block: weighted sum of -log(clip(x)) over all diag entries.
__global__ __launch_bounds__(256) void finalize_kernel(
    const float* __restrict__ text_acc,
    const float* __restrict__ vis_acc,
    float* __restrict__ out)
{
    const int tid = threadIdx.x;
    const float wt = 0.25f / (float)(B * NT);
    const float wv = 0.25f / (float)(B * NV);

    float s = 0.f;
    for (int i = tid; i < TEXT_N; i += 256) {
        float x = text_acc[i];
        x = fminf(fmaxf(x, 1e-8f), 1.0f);
        s += -logf(x) * wt;
    }
    for (int i = tid; i < VIS_N; i += 256) {
        float x = vis_acc[i];
        x = fminf(fmaxf(x, 1e-8f), 1.0f);
        s += -logf(x) * wv;
    }

#pragma unroll
    for (int off = 32; off > 0; off >>= 1) s += __shfl_down(s, off, 64);

    __shared__ float wsum[4];
    if ((tid & 63) == 0) wsum[tid >> 6] = s;
    __syncthreads();
    if (tid == 0) out[0] = wsum[0] + wsum[1] + wsum[2] + wsum[3];
}

__global__ void zero_ws_kernel(float* __restrict__ ws, int n) {
    int i = blockIdx.x * blockDim.x + threadIdx.x;
    if (i < n) ws[i] = 0.0f;
}

extern "C" void kernel_launch(void* const* d_in, const int* in_sizes, int n_in,
                              void* d_out, int out_size, void* d_ws, size_t ws_size,
                              hipStream_t stream) {
    const float* t0 = (const float*)d_in[0];
    const float* v0 = (const float*)d_in[1];
    const float* t1 = (const float*)d_in[2];
    const float* v1 = (const float*)d_in[3];
    float* out = (float*)d_out;

    constexpr size_t S_FLOATS = (size_t)4 * B * MN;                 // 9,437,184
    constexpr size_t NEED = (S_FLOATS + ACC_N) * sizeof(float);

    if (ws_size >= NEED) {
        // -------- phase-split path --------
        float* S        = (float*)d_ws;
        float* text_acc = S + S_FLOATS;
        float* vis_acc  = text_acc + TEXT_N;

        // headsum also zeroes the accumulator region (blocks 0..67)
        headsum_kernel<<<NBLK, 256, 0, stream>>>(t0, v0, t1, v1, S, text_acc);
        {
            dim3 grid(NV / TILE, NT / TILE, 2 * B);  // (9, 8, 16)
            diag_kernel<<<grid, 256, 0, stream>>>(S, text_acc, vis_acc);
        }
        finalize_kernel<<<1, 256, 0, stream>>>(text_acc, vis_acc, out);
    } else {
        // -------- fallback: original fused path --------
        float* text_acc = (float*)d_ws;
        float* vis_acc  = text_acc + TEXT_N;

        zero_ws_kernel<<<(ACC_N + 255) / 256, 256, 0, stream>>>(text_acc, ACC_N);
        {
            dim3 grid(NV / TILE, NT / TILE, 2 * B);
            fused_diag_kernel<<<grid, 256, 0, stream>>>(t0, v0, t1, v1, text_acc, vis_acc);
        }
        finalize_kernel<<<1, 256, 0, stream>>>(text_acc, vis_acc, out);
    }
}

// Round 7
// 488.950 us; speedup vs baseline: 1.0770x; 1.0142x over previous
//
#include <hip/hip_runtime.h>
#include <math.h>

// Shapes fixed by reference setup_inputs()
constexpr int B  = 8;
constexpr int H  = 16;
constexpr int NT = 512;
constexpr int NV = 576;
constexpr int TILE = 64;
constexpr float INV_H2 = 1.0f / (float)(H * H);

constexpr int MN  = NT * NV;        // 294912 elements per (b,h) plane
constexpr int MN4 = MN / 4;         // 73728 float4 per plane
constexpr int W4  = B * MN4;        // 589824 float4 per tensor head-sum
constexpr int TOTAL4 = 4 * W4;      // 2359296 float4 outputs (t0,v0,t1,v1)

// Phase-1 blocking: OUT4 float4 per thread; 2304 blocks = 9 blocks/CU exactly.
constexpr int OUT4 = 4;
constexpr int SEG4 = 256 * OUT4;    // 1024 float4 = 16 KB of outputs per block
constexpr int SEGS = MN4 / SEG4;    // 72 segments per (tensor, b) plane
constexpr int NBLK = TOTAL4 / SEG4; // 2304 blocks

// Native vector type: __builtin_nontemporal_load requires a native vector,
// not HIP's HIP_vector_type<float,4> class.
typedef float f32x4 __attribute__((ext_vector_type(4)));

// accumulator layout: text_acc[2][B][NT] then vis_acc[2][B][NV]
constexpr int TEXT_N = 2 * B * NT;  // 8192
constexpr int VIS_N  = 2 * B * NV;  // 9216
constexpr int ACC_N  = TEXT_N + VIS_N;          // 17408 = 68 * 256
constexpr int ZERO_BLKS = ACC_N / 256;          // 68 blocks zero the accs

// ---------------- Phase 1: head-sum reduction --------------------------
// (unchanged from round 5 — 122 µs ≈ 5.25 TB/s delivered, ~83% of copy
// ceiling; judged at its practical roofline)
__global__ __launch_bounds__(256) void headsum_kernel(
    const float* __restrict__ t0, const float* __restrict__ v0,
    const float* __restrict__ t1, const float* __restrict__ v1,
    float* __restrict__ S,       // [4][B][MN], order t0,v0,t1,v1
    float* __restrict__ acc_ws)  // [ACC_N] accumulators to zero
{
    const int bid  = blockIdx.x;           // 0 .. NBLK-1
    if (bid < ZERO_BLKS) {
        acc_ws[bid * 256 + threadIdx.x] = 0.0f;
    }

    const int seg  = bid % SEGS;
    const int rem  = bid / SEGS;
    const int b    = rem & (B - 1);
    const int tsel = rem >> 3;             // 0..3
    const float* __restrict__ src = (tsel == 0) ? t0 : (tsel == 1) ? v0
                                  : (tsel == 2) ? t1 : v1;

    const int p4 = seg * SEG4 + threadIdx.x;   // base float4 index in plane
    const f32x4* __restrict__ p =
        (const f32x4*)src + (size_t)b * (H * MN4) + p4;

    f32x4 acc[OUT4];
#pragma unroll
    for (int j = 0; j < OUT4; ++j) acc[j] = (f32x4)(0.f);

#pragma unroll 4
    for (int h = 0; h < H; ++h) {
        const f32x4* __restrict__ q = p + (size_t)h * MN4;
        f32x4 x[OUT4];
#pragma unroll
        for (int j = 0; j < OUT4; ++j)
            x[j] = __builtin_nontemporal_load(&q[j * 256]);
#pragma unroll
        for (int j = 0; j < OUT4; ++j)
            acc[j] += x[j];
    }

    f32x4* __restrict__ o = (f32x4*)S + ((size_t)tsel * B + b) * MN4 + p4;
#pragma unroll
    for (int j = 0; j < OUT4; ++j) o[j * 256] = acc[j];
}

// ---------------- Phase 2: diagonal products (shuffle-reduce) ----------
// One block per (k-tile, i-tile, b+B*layer). v tile transposed through LDS
// (single barrier), then Q[ii][kk] = St[ii][kk]*Sv[kk][ii] reduced by wave
// shuffles:
//   rows: 16 contiguous lanes share row ii -> xor 1,2,4,8; c==0 lane emits
//         one global atomic per row (64/block).
//   cols: lanes differing by 16,32 in a wave share col kk -> xor 16,32;
//         lanes 0-15 of each wave emit per-wave global atomics (256/block).
// No LDS atomics, no second __syncthreads.
__global__ __launch_bounds__(256) void diag_kernel(
    const float* __restrict__ S,   // [4][B][MN]
    float* __restrict__ text_acc,  // [2][B][NT]
    float* __restrict__ vis_acc)   // [2][B][NV]
{
    const int ktile = blockIdx.x;   // 0..NV/TILE-1
    const int itile = blockIdx.y;   // 0..NT/TILE-1
    const int bz    = blockIdx.z;   // 0..2*B-1
    const int b     = bz & (B - 1);
    const int layer = bz >> 3;

    const float* __restrict__ St = S + ((size_t)(2 * layer)     * B + b) * MN; // [NT][NV]
    const float* __restrict__ Sv = S + ((size_t)(2 * layer + 1) * B + b) * MN; // [NV][NT]

    const int tid = threadIdx.x;
    const int c = tid & 15;   // column group: floats 4c..4c+3
    const int g = tid >> 4;   // row group: rows g, g+16, g+32, g+48

    const int i0 = itile * TILE;
    const int k0 = ktile * TILE;

    float4 tacc[4];
    float4 vacc[4];
#pragma unroll
    for (int r = 0; r < 4; ++r) {
        const int row = g + 16 * r;
        tacc[r] = *(const float4*)(St + (size_t)(i0 + row) * NV + k0 + 4 * c);
        vacc[r] = *(const float4*)(Sv + (size_t)(k0 + row) * NT + i0 + 4 * c);
    }

    // LDS: v tile transposed access. Row stride 65 -> 2-way bank alias (free).
    __shared__ float vlds[TILE * 65];

#pragma unroll
    for (int r = 0; r < 4; ++r) {
        const int kk = g + 16 * r;          // v row index (NV dim within tile)
        float* p = &vlds[kk * 65 + 4 * c];  // cols ii = 4c..4c+3 (NT dim)
        p[0] = vacc[r].x; p[1] = vacc[r].y; p[2] = vacc[r].z; p[3] = vacc[r].w;
    }
    __syncthreads();

    // Q[ii][kk] = St[ii][kk] * Sv[kk][ii]; thread's t element:
    // ii = g+16r, kk = 4c+j.
    float colpart[4] = {0.f, 0.f, 0.f, 0.f};
    float rp[4];
#pragma unroll
    for (int r = 0; r < 4; ++r) {
        const int ii = g + 16 * r;
        const float tq[4] = {tacc[r].x, tacc[r].y, tacc[r].z, tacc[r].w};
        rp[r] = 0.f;
#pragma unroll
        for (int j = 0; j < 4; ++j) {
            const int kk = 4 * c + j;
            const float q = tq[j] * vlds[kk * 65 + ii];
            rp[r] += q;
            colpart[j] += q;
        }
    }

    const int lb = layer * B + b;

    // ---- row reduction: 16 contiguous lanes (c=0..15, same g) per row ----
#pragma unroll
    for (int off = 1; off < 16; off <<= 1) {
#pragma unroll
        for (int r = 0; r < 4; ++r) rp[r] += __shfl_xor(rp[r], off, 64);
    }
    if (c == 0) {
#pragma unroll
        for (int r = 0; r < 4; ++r) {
            atomicAdd(&text_acc[(size_t)lb * NT + i0 + g + 16 * r],
                      rp[r] * INV_H2);
        }
    }

    // ---- col reduction: lanes {c, c+16, c+32, c+48} in a wave share cols --
#pragma unroll
    for (int off = 16; off < 64; off <<= 1) {
#pragma unroll
        for (int j = 0; j < 4; ++j) colpart[j] += __shfl_xor(colpart[j], off, 64);
    }
    if ((tid & 63) < 16) {   // lanes 0..15 of each of the 4 waves
#pragma unroll
        for (int j = 0; j < 4; ++j) {
            atomicAdd(&vis_acc[(size_t)lb * NV + k0 + 4 * c + j],
                      colpart[j] * INV_H2);
        }
    }
}

// ---------------- Fallback: original fused kernel ----------------------
// Used only if ws_size cannot hold the 37.7 MB head-sum intermediate.
__global__ __launch_bounds__(256) void fused_diag_kernel(
    const float* __restrict__ t0, const float* __restrict__ v0,
    const float* __restrict__ t1, const float* __restrict__ v1,
    float* __restrict__ text_acc,   // [2][B][NT]
    float* __restrict__ vis_acc)    // [2][B][NV]
{
    const int ktile = blockIdx.x;
    const int itile = blockIdx.y;
    const int bz    = blockIdx.z;
    const int b     = bz & (B - 1);
    const int layer = bz >> 3;

    const float* __restrict__ T = layer ? t1 : t0;
    const float* __restrict__ V = layer ? v1 : v0;

    const int tid = threadIdx.x;
    const int c = tid & 15;
    const int g = tid >> 4;

    const int i0 = itile * TILE;
    const int k0 = ktile * TILE;

    const size_t tbase = (size_t)b * H * NT * NV + (size_t)i0 * NV + k0;
    const size_t vbase = (size_t)b * H * NV * NT + (size_t)k0 * NT + i0;

    float4 tacc[4];
    float4 vacc[4];
#pragma unroll
    for (int r = 0; r < 4; ++r) {
        tacc[r] = make_float4(0.f, 0.f, 0.f, 0.f);
        vacc[r] = make_float4(0.f, 0.f, 0.f, 0.f);
    }

    for (int h = 0; h < H; ++h) {
        const float* tp = T + tbase + (size_t)h * NT * NV;
        const float* vp = V + vbase + (size_t)h * NV * NT;
#pragma unroll
        for (int r = 0; r < 4; ++r) {
            const int row = g + 16 * r;
            const float4 tv = *(const float4*)(tp + (size_t)row * NV + 4 * c);
            const float4 vv = *(const float4*)(vp + (size_t)row * NT + 4 * c);
            tacc[r].x += tv.x; tacc[r].y += tv.y; tacc[r].z += tv.z; tacc[r].w += tv.w;
            vacc[r].x += vv.x; vacc[r].y += vv.y; vacc[r].z += vv.z; vacc[r].w += vv.w;
        }
    }

    __shared__ float vlds[TILE * 65];
    __shared__ float rowsum[TILE];
    __shared__ float colsum[TILE];

    if (tid < TILE) {
        rowsum[tid] = 0.0f;
        colsum[tid] = 0.0f;
    }

#pragma unroll
    for (int r = 0; r < 4; ++r) {
        const int kk = g + 16 * r;
        float* p = &vlds[kk * 65 + 4 * c];
        p[0] = vacc[r].x; p[1] = vacc[r].y; p[2] = vacc[r].z; p[3] = vacc[r].w;
    }
    __syncthreads();

    float colpart[4] = {0.f, 0.f, 0.f, 0.f};
#pragma unroll
    for (int r = 0; r < 4; ++r) {
        const int ii = g + 16 * r;
        const float tq[4] = {tacc[r].x, tacc[r].y, tacc[r].z, tacc[r].w};
        float rp = 0.f;
#pragma unroll
        for (int j = 0; j < 4; ++j) {
            const int kk = 4 * c + j;
            const float q = tq[j] * vlds[kk * 65 + ii];
            rp += q;
            colpart[j] += q;
        }
        atomicAdd(&rowsum[ii], rp);
    }
#pragma unroll
    for (int j = 0; j < 4; ++j) {
        atomicAdd(&colsum[4 * c + j], colpart[j]);
    }
    __syncthreads();

    const int lb = layer * B + b;
    if (tid < TILE) {
        atomicAdd(&text_acc[(size_t)lb * NT + i0 + tid], rowsum[tid] * INV_H2);
    } else if (tid < 2 * TILE) {
        const int kk = tid - TILE;
        atomicAdd(&vis_acc[(size_t)lb * NV + k0 + kk], colsum[kk] * INV_H2);
    }
}

// Single block: weighted sum of -log(clip(x)) over all diag entries.
__global__ __launch_bounds__(256) void finalize_kernel(
    const float* __restrict__ text_acc,
    const float* __restrict__ vis_acc,
    float* __restrict__ out)
{
    const int tid = threadIdx.x;
    const float wt = 0.25f / (float)(B * NT);
    const float wv = 0.25f / (float)(B * NV);

    float s = 0.f;
    for (int i = tid; i < TEXT_N; i += 256) {
        float x = text_acc[i];
        x = fminf(fmaxf(x, 1e-8f), 1.0f);
        s += -logf(x) * wt;
    }
    for (int i = tid; i < VIS_N; i += 256) {
        float x = vis_acc[i];
        x = fminf(fmaxf(x, 1e-8f), 1.0f);
        s += -logf(x) * wv;
    }

#pragma unroll
    for (int off = 32; off > 0; off >>= 1) s += __shfl_down(s, off, 64);

    __shared__ float wsum[4];
    if ((tid & 63) == 0) wsum[tid >> 6] = s;
    __syncthreads();
    if (tid == 0) out[0] = wsum[0] + wsum[1] + wsum[2] + wsum[3];
}

__global__ void zero_ws_kernel(float* __restrict__ ws, int n) {
    int i = blockIdx.x * blockDim.x + threadIdx.x;
    if (i < n) ws[i] = 0.0f;
}

extern "C" void kernel_launch(void* const* d_in, const int* in_sizes, int n_in,
                              void* d_out, int out_size, void* d_ws, size_t ws_size,
                              hipStream_t stream) {
    const float* t0 = (const float*)d_in[0];
    const float* v0 = (const float*)d_in[1];
    const float* t1 = (const float*)d_in[2];
    const float* v1 = (const float*)d_in[3];
    float* out = (float*)d_out;

    constexpr size_t S_FLOATS = (size_t)4 * B * MN;                 // 9,437,184
    constexpr size_t NEED = (S_FLOATS + ACC_N) * sizeof(float);

    if (ws_size >= NEED) {
        // -------- phase-split path --------
        float* S        = (float*)d_ws;
        float* text_acc = S + S_FLOATS;
        float* vis_acc  = text_acc + TEXT_N;

        // headsum also zeroes the accumulator region (blocks 0..67)
        headsum_kernel<<<NBLK, 256, 0, stream>>>(t0, v0, t1, v1, S, text_acc);
        {
            dim3 grid(NV / TILE, NT / TILE, 2 * B);  // (9, 8, 16)
            diag_kernel<<<grid, 256, 0, stream>>>(S, text_acc, vis_acc);
        }
        finalize_kernel<<<1, 256, 0, stream>>>(text_acc, vis_acc, out);
    } else {
        // -------- fallback: original fused path --------
        float* text_acc = (float*)d_ws;
        float* vis_acc  = text_acc + TEXT_N;

        zero_ws_kernel<<<(ACC_N + 255) / 256, 256, 0, stream>>>(text_acc, ACC_N);
        {
            dim3 grid(NV / TILE, NT / TILE, 2 * B);
            fused_diag_kernel<<<grid, 256, 0, stream>>>(t0, v0, t1, v1, text_acc, vis_acc);
        }
        finalize_kernel<<<1, 256, 0, stream>>>(text_acc, vis_acc, out);
    }
}